// Round 2
// baseline (409.039 us; speedup 1.0000x reference)
//
#include <hip/hip_runtime.h>

#define BB 8
#define NN 1024
#define DIN 64
#define DOUT 64
#define EMB 16
#define DPC 16

// ---------------- Kernel A: sim = softmax_rows(relu(E E^T)) ----------------
__global__ __launch_bounds__(256) void k_sim(const float* __restrict__ E,
                                             float* __restrict__ sim) {
    const int i = blockIdx.x;
    const int tid = threadIdx.x;
    __shared__ float rbuf[NN];
    __shared__ float red[256];

    float4 ei0 = *(const float4*)&E[i*EMB + 0];
    float4 ei1 = *(const float4*)&E[i*EMB + 4];
    float4 ei2 = *(const float4*)&E[i*EMB + 8];
    float4 ei3 = *(const float4*)&E[i*EMB + 12];

    float rv[4];
    float tmax = -1e30f;
    #pragma unroll
    for (int k = 0; k < 4; ++k) {
        int j = tid + k*256;
        float4 a0 = *(const float4*)&E[j*EMB + 0];
        float4 a1 = *(const float4*)&E[j*EMB + 4];
        float4 a2 = *(const float4*)&E[j*EMB + 8];
        float4 a3 = *(const float4*)&E[j*EMB + 12];
        float s = ei0.x*a0.x + ei0.y*a0.y + ei0.z*a0.z + ei0.w*a0.w
                + ei1.x*a1.x + ei1.y*a1.y + ei1.z*a1.z + ei1.w*a1.w
                + ei2.x*a2.x + ei2.y*a2.y + ei2.z*a2.z + ei2.w*a2.w
                + ei3.x*a3.x + ei3.y*a3.y + ei3.z*a3.z + ei3.w*a3.w;
        s = fmaxf(s, 0.0f);
        rv[k] = s;
        tmax = fmaxf(tmax, s);
    }
    red[tid] = tmax;
    __syncthreads();
    for (int s = 128; s > 0; s >>= 1) {
        if (tid < s) red[tid] = fmaxf(red[tid], red[tid + s]);
        __syncthreads();
    }
    float rmax = red[0];
    __syncthreads();

    float tsum = 0.0f;
    #pragma unroll
    for (int k = 0; k < 4; ++k) {
        float e = __expf(rv[k] - rmax);
        rbuf[tid + k*256] = e;
        tsum += e;
    }
    red[tid] = tsum;
    __syncthreads();
    for (int s = 128; s > 0; s >>= 1) {
        if (tid < s) red[tid] += red[tid + s];
        __syncthreads();
    }
    float inv = 1.0f / red[0];
    #pragma unroll
    for (int k = 0; k < 4; ++k)
        sim[i*NN + tid + k*256] = rbuf[tid + k*256] * inv;
}

// ------------- Kernel B: Z[b,c] = sum_j exp(-L1(pa[c],pa[j])); xz = x / Z -------------
__global__ __launch_bounds__(256) void k_z_xz(const float* __restrict__ pa,
                                              const float* __restrict__ x,
                                              float* __restrict__ xz) {
    const int b  = blockIdx.y;
    const int c0 = blockIdx.x * 64;
    const int tid = threadIdx.x;
    __shared__ float pa_l[512 * DPC];
    __shared__ float zpart[4][64];
    __shared__ float invZ[64];

    const int cs = tid & 63, jq = tid >> 6;
    float myc[DPC];
    #pragma unroll
    for (int p = 0; p < DPC; ++p) myc[p] = pa[b*NN*DPC + (c0 + cs)*DPC + p];

    float part = 0.0f;
    for (int h = 0; h < 2; ++h) {
        __syncthreads();
        for (int idx = tid; idx < 512*DPC/4; idx += 256)
            ((float4*)pa_l)[idx] = ((const float4*)(pa + b*NN*DPC + h*512*DPC))[idx];
        __syncthreads();
        for (int jj = jq*128; jj < jq*128 + 128; ++jj) {
            float s = 0.0f;
            #pragma unroll
            for (int p = 0; p < DPC; ++p) s += fabsf(myc[p] - pa_l[jj*DPC + p]);
            part += __expf(-s);
        }
    }
    zpart[jq][cs] = part;
    __syncthreads();
    if (tid < 64) {
        float z = zpart[0][tid] + zpart[1][tid] + zpart[2][tid] + zpart[3][tid];
        invZ[tid] = 1.0f / z;
    }
    __syncthreads();
    for (int idx = tid; idx < 64*DIN; idx += 256) {
        int c = idx >> 6, d = idx & 63;
        xz[b*NN*DIN + (c0 + c)*DIN + d] = x[b*NN*DIN + (c0 + c)*DIN + d] * invZ[c];
    }
}

// ------------- Kernel C: sx += (c-split) exp(-L1) @ xz -------------
// tile: 256 m x 64 d, c-range 128 per block, 8m x 8d per thread.
#define XSTR 68
#define WSTR 260
__global__ __launch_bounds__(256, 2) void k_sx2(const float* __restrict__ pa,
                                                const float* __restrict__ xz,
                                                float* __restrict__ sx) {
    const int mt = blockIdx.x >> 3, cspl = blockIdx.x & 7;
    const int b  = blockIdx.y;
    const int m0 = mt * 256, c0 = cspl * 128;
    const int tid = threadIdx.x;

    __shared__ __align__(16) float xz_l[128 * XSTR];
    __shared__ __align__(16) float wt[32 * WSTR];
    __shared__ __align__(16) float pa_c[32 * DPC];

    float pam[DPC];
    #pragma unroll
    for (int p4 = 0; p4 < 4; ++p4) {
        float4 t = *(const float4*)&pa[b*NN*DPC + (m0 + tid)*DPC + p4*4];
        pam[p4*4+0] = t.x; pam[p4*4+1] = t.y; pam[p4*4+2] = t.z; pam[p4*4+3] = t.w;
    }
    for (int idx = tid; idx < 128*16; idx += 256) {
        int c = idx >> 4, f = idx & 15;
        *(float4*)&xz_l[c*XSTR + f*4] =
            *(const float4*)&xz[b*NN*DIN + (c0 + c)*DIN + f*4];
    }

    const int mg = tid >> 3, dg = tid & 7;
    float acc[8][8];
    #pragma unroll
    for (int j = 0; j < 8; ++j)
        #pragma unroll
        for (int k = 0; k < 8; ++k) acc[j][k] = 0.0f;

    for (int sc = 0; sc < 4; ++sc) {
        __syncthreads();
        if (tid < 128) {
            int c = tid >> 2, f = tid & 3;
            *(float4*)&pa_c[c*DPC + f*4] =
                *(const float4*)&pa[b*NN*DPC + (c0 + sc*32 + c)*DPC + f*4];
        }
        __syncthreads();
        #pragma unroll 4
        for (int c = 0; c < 32; ++c) {
            float s = 0.0f;
            #pragma unroll
            for (int p4 = 0; p4 < 4; ++p4) {
                float4 q = *(const float4*)&pa_c[c*DPC + p4*4];
                s += fabsf(pam[p4*4+0] - q.x) + fabsf(pam[p4*4+1] - q.y)
                   + fabsf(pam[p4*4+2] - q.z) + fabsf(pam[p4*4+3] - q.w);
            }
            wt[c*WSTR + tid] = __expf(-s);
        }
        __syncthreads();
        #pragma unroll 2
        for (int cc = 0; cc < 32; ++cc) {
            float4 w0 = *(const float4*)&wt[cc*WSTR + mg*8];
            float4 w1 = *(const float4*)&wt[cc*WSTR + mg*8 + 4];
            float4 x0 = *(const float4*)&xz_l[(sc*32 + cc)*XSTR + dg*8];
            float4 x1 = *(const float4*)&xz_l[(sc*32 + cc)*XSTR + dg*8 + 4];
            float wv[8] = {w0.x, w0.y, w0.z, w0.w, w1.x, w1.y, w1.z, w1.w};
            float xv[8] = {x0.x, x0.y, x0.z, x0.w, x1.x, x1.y, x1.z, x1.w};
            #pragma unroll
            for (int j = 0; j < 8; ++j)
                #pragma unroll
                for (int k = 0; k < 8; ++k) acc[j][k] += wv[j] * xv[k];
        }
    }
    #pragma unroll
    for (int j = 0; j < 8; ++j) {
        float* dst = sx + b*NN*DIN + (m0 + mg*8 + j)*DIN + dg*8;
        #pragma unroll
        for (int k = 0; k < 8; ++k) atomicAdd(&dst[k], acc[j][k]);
    }
}

// ------------- Kernel D: y += (c-split) sim @ sx -------------
__global__ __launch_bounds__(256, 2) void k_y2(const float* __restrict__ sim,
                                               const float* __restrict__ sxin,
                                               float* __restrict__ y) {
    const int mt = blockIdx.x >> 3, cspl = blockIdx.x & 7;
    const int b  = blockIdx.y;
    const int m0 = mt * 256, c0 = cspl * 128;
    const int tid = threadIdx.x;

    __shared__ __align__(16) float sx_l[128 * XSTR];
    __shared__ __align__(16) float wt[32 * WSTR];

    for (int idx = tid; idx < 128*16; idx += 256) {
        int c = idx >> 4, f = idx & 15;
        *(float4*)&sx_l[c*XSTR + f*4] =
            *(const float4*)&sxin[b*NN*DIN + (c0 + c)*DIN + f*4];
    }

    const int mg = tid >> 3, dg = tid & 7;
    float acc[8][8];
    #pragma unroll
    for (int j = 0; j < 8; ++j)
        #pragma unroll
        for (int k = 0; k < 8; ++k) acc[j][k] = 0.0f;

    for (int sc = 0; sc < 4; ++sc) {
        __syncthreads();
        for (int idx = tid; idx < 2048; idx += 256) {
            int m = idx >> 3, cq = idx & 7;
            float4 v = *(const float4*)&sim[(m0 + m)*NN + c0 + sc*32 + cq*4];
            wt[(cq*4 + 0)*WSTR + m] = v.x;
            wt[(cq*4 + 1)*WSTR + m] = v.y;
            wt[(cq*4 + 2)*WSTR + m] = v.z;
            wt[(cq*4 + 3)*WSTR + m] = v.w;
        }
        __syncthreads();
        #pragma unroll 2
        for (int cc = 0; cc < 32; ++cc) {
            float4 w0 = *(const float4*)&wt[cc*WSTR + mg*8];
            float4 w1 = *(const float4*)&wt[cc*WSTR + mg*8 + 4];
            float4 x0 = *(const float4*)&sx_l[(sc*32 + cc)*XSTR + dg*8];
            float4 x1 = *(const float4*)&sx_l[(sc*32 + cc)*XSTR + dg*8 + 4];
            float wv[8] = {w0.x, w0.y, w0.z, w0.w, w1.x, w1.y, w1.z, w1.w};
            float xv[8] = {x0.x, x0.y, x0.z, x0.w, x1.x, x1.y, x1.z, x1.w};
            #pragma unroll
            for (int j = 0; j < 8; ++j)
                #pragma unroll
                for (int k = 0; k < 8; ++k) acc[j][k] += wv[j] * xv[k];
        }
    }
    #pragma unroll
    for (int j = 0; j < 8; ++j) {
        float* dst = y + b*NN*DIN + (m0 + mg*8 + j)*DIN + dg*8;
        #pragma unroll
        for (int k = 0; k < 8; ++k) atomicAdd(&dst[k], acc[j][k]);
    }
}

__device__ inline unsigned short f2bf(float f) {
    unsigned u = __float_as_uint(f);
    u += 0x7fffu + ((u >> 16) & 1u);
    return (unsigned short)(u >> 16);
}

// ------------- Kernel E1: W2[n][kio] (bf16) = sum_d E[n,d] * wp[d][kio] -------------
__global__ __launch_bounds__(256) void k_wgen(const float* __restrict__ E,
                                              const float* __restrict__ wp,
                                              unsigned short* __restrict__ W2) {
    const int tid = threadIdx.x;
    const int kio0 = blockIdx.x * 1024 + tid * 4;
    const int n0 = blockIdx.y * 32;
    __shared__ float El[32 * EMB];
    if (tid < 128) *(float4*)&El[tid*4] = *(const float4*)&E[n0*EMB + tid*4];

    float4 wq[EMB];
    #pragma unroll
    for (int d = 0; d < EMB; ++d)
        wq[d] = *(const float4*)&wp[d*8192 + kio0];
    __syncthreads();

    for (int n = 0; n < 32; ++n) {
        float4 a = make_float4(0.f, 0.f, 0.f, 0.f);
        #pragma unroll
        for (int d = 0; d < EMB; ++d) {
            float e = El[n*EMB + d];
            a.x += e*wq[d].x; a.y += e*wq[d].y; a.z += e*wq[d].z; a.w += e*wq[d].w;
        }
        ushort4 us = make_ushort4(f2bf(a.x), f2bf(a.y), f2bf(a.z), f2bf(a.w));
        *(ushort4*)&W2[(size_t)(n0 + n)*8192 + kio0] = us;
    }
}

// ------------- Kernel E2: out[b,n,o] = sum_ki v[b,n,ki] W2[n,ki,o] + E[n]@bp -------------
__global__ __launch_bounds__(256) void k_out2(const float* __restrict__ E,
                                              const float* __restrict__ bp,
                                              const unsigned short* __restrict__ W2,
                                              const float* __restrict__ sxin,
                                              const float* __restrict__ yin,
                                              float* __restrict__ out) {
    const int n = blockIdx.x;
    const int tid = threadIdx.x;
    __shared__ __align__(16) uint4 W2l4[1024];
    __shared__ float vl[BB * 128];
    __shared__ float El2[EMB];

    if (tid < EMB) El2[tid] = E[n*EMB + tid];
    {
        const uint4* src = (const uint4*)(W2 + (size_t)n * 8192);
        #pragma unroll
        for (int r = 0; r < 4; ++r) W2l4[tid + r*256] = src[tid + r*256];
    }
    for (int idx = tid; idx < BB*128; idx += 256) {
        int b_ = idx >> 7, ki = idx & 127;
        vl[idx] = (ki < 64) ? sxin[(b_*NN + n)*DIN + ki]
                            : yin[(b_*NN + n)*DIN + (ki - 64)];
    }
    __syncthreads();

    const int b_ = tid >> 5, op = (tid & 31) * 2;
    const unsigned* W2u = (const unsigned*)W2l4;
    float a0 = 0.f, a1 = 0.f;
    #pragma unroll 4
    for (int ki = 0; ki < 128; ++ki) {
        float vv = vl[b_*128 + ki];
        unsigned w2 = W2u[ki*32 + (op >> 1)];
        float f0 = __uint_as_float(w2 << 16);
        float f1 = __uint_as_float(w2 & 0xffff0000u);
        a0 += vv * f0;
        a1 += vv * f1;
    }
    float b0 = 0.f, b1 = 0.f;
    #pragma unroll
    for (int d = 0; d < EMB; ++d) {
        float e = El2[d];
        b0 += e * bp[d*DOUT + op];
        b1 += e * bp[d*DOUT + op + 1];
    }
    float2 st = make_float2(a0 + b0, a1 + b1);
    *(float2*)&out[(size_t)(b_*NN + n)*DOUT + op] = st;
}

// ------------- Fallback (round-1 k_out) if ws too small for W2 -------------
#define NSTRIDE 516
__global__ __launch_bounds__(256) void k_out_fb(const float* __restrict__ E,
                                                const float* __restrict__ wp,
                                                const float* __restrict__ bp,
                                                const float* __restrict__ sxin,
                                                const float* __restrict__ yin,
                                                float* __restrict__ out) {
    const int n0 = blockIdx.x * 4;
    const int tid = threadIdx.x;
    __shared__ __align__(16) float wpch[16 * 8 * 64];
    __shared__ __align__(16) float Wl[4 * NSTRIDE];
    __shared__ float vch[32 * 8];
    __shared__ float El[4 * 16];

    if (tid < 64) El[tid] = E[n0*EMB + tid];

    const int bn = tid >> 3, og = tid & 7;
    const int b = bn >> 2, nsub = bn & 3;
    float acc[8];
    #pragma unroll
    for (int k = 0; k < 8; ++k) acc[k] = 0.0f;

    for (int ic = 0; ic < 16; ++ic) {
        __syncthreads();
        for (int idx = tid; idx < 2048; idx += 256) {
            int d = idx >> 7, isub = (idx >> 4) & 7, o4 = idx & 15;
            int gi = ic*8 + isub;
            int k = gi >> 6, i0 = gi & 63;
            ((float4*)wpch)[idx] = ((const float4*)wp)[((d*2 + k)*64 + i0)*16 + o4];
        }
        {
            int vbn = tid >> 3, visub = tid & 7;
            int vb = vbn >> 2, vns = vbn & 3;
            int nidx = (vb*NN + (n0 + vns))*DIN;
            float val;
            if (ic < 8) val = sxin[nidx + ic*8 + visub];
            else        val = yin[nidx + (ic - 8)*8 + visub];
            vch[vbn*8 + visub] = val;
        }
        __syncthreads();
        for (int e = tid; e < 512; e += 256) {
            int ns = e >> 7, isub = (e >> 4) & 7, o4 = e & 15;
            float4 s = make_float4(0.f, 0.f, 0.f, 0.f);
            #pragma unroll
            for (int d = 0; d < EMB; ++d) {
                float ev = El[ns*16 + d];
                const float4 w = *(const float4*)&wpch[(d*8 + isub)*64 + o4*4];
                s.x += ev*w.x; s.y += ev*w.y; s.z += ev*w.z; s.w += ev*w.w;
            }
            *(float4*)&Wl[ns*NSTRIDE + isub*64 + o4*4] = s;
        }
        __syncthreads();
        #pragma unroll
        for (int isub = 0; isub < 8; ++isub) {
            float wv = vch[bn*8 + isub];
            const float4 w0 = *(const float4*)&Wl[nsub*NSTRIDE + isub*64 + og*8];
            const float4 w1 = *(const float4*)&Wl[nsub*NSTRIDE + isub*64 + og*8 + 4];
            acc[0] += wv*w0.x; acc[1] += wv*w0.y; acc[2] += wv*w0.z; acc[3] += wv*w0.w;
            acc[4] += wv*w1.x; acc[5] += wv*w1.y; acc[6] += wv*w1.z; acc[7] += wv*w1.w;
        }
    }
    float4 bv0 = make_float4(0.f, 0.f, 0.f, 0.f);
    float4 bv1 = make_float4(0.f, 0.f, 0.f, 0.f);
    #pragma unroll
    for (int d = 0; d < EMB; ++d) {
        float ev = El[nsub*16 + d];
        const float4 p0 = *(const float4*)&bp[d*DOUT + og*8];
        const float4 p1 = *(const float4*)&bp[d*DOUT + og*8 + 4];
        bv0.x += ev*p0.x; bv0.y += ev*p0.y; bv0.z += ev*p0.z; bv0.w += ev*p0.w;
        bv1.x += ev*p1.x; bv1.y += ev*p1.y; bv1.z += ev*p1.z; bv1.w += ev*p1.w;
    }
    float* dst = out + (b*NN + (n0 + nsub))*DOUT + og*8;
    *(float4*)dst       = make_float4(acc[0]+bv0.x, acc[1]+bv0.y, acc[2]+bv0.z, acc[3]+bv0.w);
    *(float4*)(dst + 4) = make_float4(acc[4]+bv1.x, acc[5]+bv1.y, acc[6]+bv1.z, acc[7]+bv1.w);
}

extern "C" void kernel_launch(void* const* d_in, const int* in_sizes, int n_in,
                              void* d_out, int out_size, void* d_ws, size_t ws_size,
                              hipStream_t stream) {
    (void)in_sizes; (void)n_in; (void)out_size;
    const float* x  = (const float*)d_in[0];
    const float* E  = (const float*)d_in[1];
    const float* pa = (const float*)d_in[2];
    const float* wp = (const float*)d_in[3];
    const float* bp = (const float*)d_in[4];
    float* out = (float*)d_out;

    float* ws  = (float*)d_ws;
    float* sim = ws;
    float* xz  = sim + NN*NN;
    float* sx  = xz + BB*NN*DIN;
    float* y   = sx + BB*NN*DIN;
    unsigned short* W2 = (unsigned short*)(y + BB*NN*DIN);

    const size_t base_bytes = ((size_t)NN*NN + 3ull*BB*NN*DIN) * 4ull;            // 10 MiB
    const size_t big_bytes  = base_bytes + (size_t)NN * 2 * DIN * DOUT * 2ull;    // +16 MiB
    const bool use_big = (ws_size >= big_bytes);

    hipMemsetAsync(sx, 0, (size_t)BB*NN*DIN*4, stream);
    hipMemsetAsync(y,  0, (size_t)BB*NN*DIN*4, stream);

    k_sim<<<NN, 256, 0, stream>>>(E, sim);
    k_z_xz<<<dim3(16, BB), 256, 0, stream>>>(pa, x, xz);
    k_sx2<<<dim3(32, BB), 256, 0, stream>>>(pa, xz, sx);
    k_y2<<<dim3(32, BB), 256, 0, stream>>>(sim, sx, y);
    if (use_big) {
        k_wgen<<<dim3(8, 32), 256, 0, stream>>>(E, wp, W2);
        k_out2<<<NN, 256, 0, stream>>>(E, bp, W2, sx, y, out);
    } else {
        k_out_fb<<<NN/4, 256, 0, stream>>>(E, wp, bp, sx, y, out);
    }
}

// Round 3
// 145.036 us; speedup vs baseline: 2.8203x; 2.8203x over previous
//
#include <hip/hip_runtime.h>

#define BB 8
#define NN 1024
#define DIN 64
#define DOUT 64
#define EMB 16
#define DPC 16

typedef __attribute__((ext_vector_type(8))) short bf16x8;
typedef __attribute__((ext_vector_type(4))) float f32x4;

__device__ inline unsigned short f2bf(float f) {
    unsigned u = __float_as_uint(f);
    u += 0x7fffu + ((u >> 16) & 1u);      // RNE (finite only)
    return (unsigned short)(u >> 16);
}

// ---------------- k_sim2: sim_bf[m][c] = bf16(softmax_rows(relu(E E^T))) ----------------
__global__ __launch_bounds__(256) void k_sim2(const float* __restrict__ E,
                                              unsigned short* __restrict__ sim_bf) {
    const int i = blockIdx.x, tid = threadIdx.x;
    const int lane = tid & 63, wave = tid >> 6;
    __shared__ float redw[4];

    float4 ei0 = *(const float4*)&E[i*EMB + 0];
    float4 ei1 = *(const float4*)&E[i*EMB + 4];
    float4 ei2 = *(const float4*)&E[i*EMB + 8];
    float4 ei3 = *(const float4*)&E[i*EMB + 12];

    float rv[4], tmax = -1e30f;
    #pragma unroll
    for (int k = 0; k < 4; ++k) {
        int j = tid + k*256;
        float4 a0 = *(const float4*)&E[j*EMB + 0];
        float4 a1 = *(const float4*)&E[j*EMB + 4];
        float4 a2 = *(const float4*)&E[j*EMB + 8];
        float4 a3 = *(const float4*)&E[j*EMB + 12];
        float s = ei0.x*a0.x + ei0.y*a0.y + ei0.z*a0.z + ei0.w*a0.w
                + ei1.x*a1.x + ei1.y*a1.y + ei1.z*a1.z + ei1.w*a1.w
                + ei2.x*a2.x + ei2.y*a2.y + ei2.z*a2.z + ei2.w*a2.w
                + ei3.x*a3.x + ei3.y*a3.y + ei3.z*a3.z + ei3.w*a3.w;
        s = fmaxf(s, 0.0f);
        rv[k] = s; tmax = fmaxf(tmax, s);
    }
    #pragma unroll
    for (int off = 32; off > 0; off >>= 1) tmax = fmaxf(tmax, __shfl_xor(tmax, off));
    if (lane == 0) redw[wave] = tmax;
    __syncthreads();
    float rmax = fmaxf(fmaxf(redw[0], redw[1]), fmaxf(redw[2], redw[3]));
    __syncthreads();

    float ev[4], tsum = 0.f;
    #pragma unroll
    for (int k = 0; k < 4; ++k) { ev[k] = __expf(rv[k] - rmax); tsum += ev[k]; }
    #pragma unroll
    for (int off = 32; off > 0; off >>= 1) tsum += __shfl_xor(tsum, off);
    if (lane == 0) redw[wave] = tsum;
    __syncthreads();
    float inv = 1.0f / (redw[0] + redw[1] + redw[2] + redw[3]);
    #pragma unroll
    for (int k = 0; k < 4; ++k)
        sim_bf[i*NN + tid + k*256] = f2bf(ev[k] * inv);
}

// ---------------- k_z2: Z[b,c] = sum_j exp(-L1); xzT[b][d][c] = bf16(x[c][d]/Z[c]) ----------------
__global__ __launch_bounds__(256) void k_z2(const float* __restrict__ pa,
                                            const float* __restrict__ x,
                                            unsigned short* __restrict__ xzT) {
    const int b = blockIdx.y, c0 = blockIdx.x * 32;
    const int tid = threadIdx.x;
    __shared__ float pa_l[512 * DPC];      // 32 KB
    __shared__ float myp[32 * DPC];
    __shared__ float zpart[8][32];
    __shared__ float xl[32 * 65];
    __shared__ float invZ[32];

    if (tid < 128)
        ((float4*)myp)[tid] = *(const float4*)&pa[((size_t)b*NN + c0)*DPC + tid*4];
    __syncthreads();

    const int cs = tid & 31, jq = tid >> 5;
    float myc[DPC];
    #pragma unroll
    for (int p4 = 0; p4 < 4; ++p4) {
        float4 t = *(const float4*)&myp[cs*DPC + p4*4];
        myc[p4*4+0] = t.x; myc[p4*4+1] = t.y; myc[p4*4+2] = t.z; myc[p4*4+3] = t.w;
    }

    float part = 0.0f;
    for (int h = 0; h < 2; ++h) {
        __syncthreads();
        for (int i = tid; i < 512*DPC/4; i += 256)
            ((float4*)pa_l)[i] = ((const float4*)(pa + ((size_t)b*NN + h*512)*DPC))[i];
        __syncthreads();
        for (int jj = jq*64; jj < jq*64 + 64; ++jj) {
            float s = 0.0f;
            #pragma unroll
            for (int p4 = 0; p4 < 4; ++p4) {
                float4 q = *(const float4*)&pa_l[jj*DPC + p4*4];
                s += fabsf(myc[p4*4+0]-q.x) + fabsf(myc[p4*4+1]-q.y)
                   + fabsf(myc[p4*4+2]-q.z) + fabsf(myc[p4*4+3]-q.w);
            }
            part += __expf(-s);
        }
    }
    zpart[jq][cs] = part;

    // stage x chunk (transpose-friendly): xl[c][d], stride 65
    __syncthreads();
    #pragma unroll
    for (int i = 0; i < 8; ++i) {
        int l = i*256 + tid, d = l & 63, c = l >> 6;
        xl[c*65 + d] = x[((size_t)b*NN + c0 + c)*DIN + d];
    }
    if (tid < 32) {
        float z = 0.f;
        #pragma unroll
        for (int q = 0; q < 8; ++q) z += zpart[q][tid];
        invZ[tid] = 1.0f / z;
    }
    __syncthreads();
    #pragma unroll
    for (int i = 0; i < 8; ++i) {
        int l = i*256 + tid, c = l & 31, d = l >> 5;
        xzT[((size_t)b*DIN + d)*NN + c0 + c] = f2bf(xl[c*65 + d] * invZ[c]);
    }
}

// ---------------- k_sx3: MFMA — sx = W_exp @ xz ; W generated on the fly ----------------
// grid (64, 8): m-tile 16, block 256 thr (4 waves). K = c, steps of 32.
#define ASTR 40
#define BSTR 40
__global__ __launch_bounds__(256, 2) void k_sx3(const float* __restrict__ pa,
                                                const unsigned short* __restrict__ xzT,
                                                float* __restrict__ sx,
                                                unsigned short* __restrict__ sxT) {
    const int b = blockIdx.y, m0 = blockIdx.x * 16;
    const int tid = threadIdx.x;
    const int lane = tid & 63, wave = tid >> 6;
    __shared__ float pa_all[NN * DPC];             // 64 KB: all prompt rows of this b
    __shared__ unsigned short A_l[16 * ASTR];
    __shared__ unsigned short BT_l[64 * BSTR];

    for (int i = tid; i < NN*DPC/4; i += 256)
        ((float4*)pa_all)[i] = ((const float4*)(pa + (size_t)b*NN*DPC))[i];
    __syncthreads();

    // exp-gen mapping: me = tid&15 (m-row), cg = tid>>4 (covers c-local cg*2..+1)
    const int me = tid & 15, cg = tid >> 4;
    float pam[DPC];
    #pragma unroll
    for (int p4 = 0; p4 < 4; ++p4) {
        float4 t = *(const float4*)&pa_all[(m0 + me)*DPC + p4*4];
        pam[p4*4+0] = t.x; pam[p4*4+1] = t.y; pam[p4*4+2] = t.z; pam[p4*4+3] = t.w;
    }

    const int q = lane >> 4, r = lane & 15;
    f32x4 acc = {0.f, 0.f, 0.f, 0.f};

    for (int kk = 0; kk < 32; ++kk) {
        const int c0 = kk * 32;
        __syncthreads();
        // stage B^T tile: xzT[b][d][c0..c0+31], 64 rows x 32 bf16
        {
            int d = tid >> 2, ch = tid & 3;
            *(uint4*)&BT_l[d*BSTR + ch*8] =
                *(const uint4*)&xzT[((size_t)b*DIN + d)*NN + c0 + ch*8];
        }
        // exp-gen: 2 entries per thread into A_l[m][c_local]
        #pragma unroll
        for (int cl = 0; cl < 2; ++cl) {
            int cloc = cg*2 + cl;
            int c = c0 + cloc;
            float s = 0.0f;
            #pragma unroll
            for (int p4 = 0; p4 < 4; ++p4) {
                float4 qv = *(const float4*)&pa_all[c*DPC + p4*4];
                s += fabsf(pam[p4*4+0]-qv.x) + fabsf(pam[p4*4+1]-qv.y)
                   + fabsf(pam[p4*4+2]-qv.z) + fabsf(pam[p4*4+3]-qv.w);
            }
            A_l[me*ASTR + cloc] = f2bf(__expf(-s));
        }
        __syncthreads();
        bf16x8 af = *(const bf16x8*)&A_l[r*ASTR + q*8];
        bf16x8 bfv = *(const bf16x8*)&BT_l[(wave*16 + r)*BSTR + q*8];
        acc = __builtin_amdgcn_mfma_f32_16x16x32_bf16(af, bfv, acc, 0, 0, 0);
    }

    // C/D: col(n=d) = lane&15, row(m) = quad*4 + reg
    const int mrow = m0 + q*4;
    const int d = wave*16 + r;
    #pragma unroll
    for (int reg = 0; reg < 4; ++reg)
        sx[((size_t)b*NN + mrow + reg)*DIN + d] = acc[reg];
    ushort4 u4 = make_ushort4(f2bf(acc[0]), f2bf(acc[1]), f2bf(acc[2]), f2bf(acc[3]));
    *(ushort4*)&sxT[((size_t)b*DIN + d)*NN + mrow] = u4;
}

// ---------------- k_y3: MFMA — y = sim_bf @ sx (B from sxT) ----------------
__global__ __launch_bounds__(256, 2) void k_y3(const unsigned short* __restrict__ sim_bf,
                                               const unsigned short* __restrict__ sxT,
                                               float* __restrict__ y) {
    const int b = blockIdx.y, m0 = blockIdx.x * 16;
    const int tid = threadIdx.x;
    const int lane = tid & 63, wave = tid >> 6;
    __shared__ unsigned short A_l[16 * ASTR];
    __shared__ unsigned short BT_l[64 * BSTR];

    const int q = lane >> 4, r = lane & 15;
    f32x4 acc = {0.f, 0.f, 0.f, 0.f};

    for (int kk = 0; kk < 32; ++kk) {
        const int c0 = kk * 32;
        __syncthreads();
        {
            int d = tid >> 2, ch = tid & 3;
            *(uint4*)&BT_l[d*BSTR + ch*8] =
                *(const uint4*)&sxT[((size_t)b*DIN + d)*NN + c0 + ch*8];
        }
        if (tid < 64) {
            int m = tid >> 2, ch = tid & 3;
            *(uint4*)&A_l[m*ASTR + ch*8] =
                *(const uint4*)&sim_bf[(size_t)(m0 + m)*NN + c0 + ch*8];
        }
        __syncthreads();
        bf16x8 af = *(const bf16x8*)&A_l[r*ASTR + q*8];
        bf16x8 bfv = *(const bf16x8*)&BT_l[(wave*16 + r)*BSTR + q*8];
        acc = __builtin_amdgcn_mfma_f32_16x16x32_bf16(af, bfv, acc, 0, 0, 0);
    }

    const int mrow = m0 + q*4;
    const int d = wave*16 + r;
    #pragma unroll
    for (int reg = 0; reg < 4; ++reg)
        y[((size_t)b*NN + mrow + reg)*DIN + d] = acc[reg];
}

// ---------------- k_wgen: W2[n][kio] (bf16) = sum_d E[n,d] * wp[d][kio] ----------------
__global__ __launch_bounds__(256) void k_wgen(const float* __restrict__ E,
                                              const float* __restrict__ wp,
                                              unsigned short* __restrict__ W2) {
    const int tid = threadIdx.x;
    const int kio0 = blockIdx.x * 1024 + tid * 4;
    const int n0 = blockIdx.y * 32;
    __shared__ float El[32 * EMB];
    if (tid < 128) *(float4*)&El[tid*4] = *(const float4*)&E[n0*EMB + tid*4];

    float4 wq[EMB];
    #pragma unroll
    for (int d = 0; d < EMB; ++d)
        wq[d] = *(const float4*)&wp[d*8192 + kio0];
    __syncthreads();

    for (int n = 0; n < 32; ++n) {
        float4 a = make_float4(0.f, 0.f, 0.f, 0.f);
        #pragma unroll
        for (int d = 0; d < EMB; ++d) {
            float e = El[n*EMB + d];
            a.x += e*wq[d].x; a.y += e*wq[d].y; a.z += e*wq[d].z; a.w += e*wq[d].w;
        }
        ushort4 us = make_ushort4(f2bf(a.x), f2bf(a.y), f2bf(a.z), f2bf(a.w));
        *(ushort4*)&W2[(size_t)(n0 + n)*8192 + kio0] = us;
    }
}

// ---------------- k_out2: out[b,n,o] = sum_ki v[b,n,ki] W2[n,ki,o] + E[n]@bp ----------------
__global__ __launch_bounds__(256) void k_out2(const float* __restrict__ E,
                                              const float* __restrict__ bp,
                                              const unsigned short* __restrict__ W2,
                                              const float* __restrict__ sxin,
                                              const float* __restrict__ yin,
                                              float* __restrict__ out) {
    const int n = blockIdx.x;
    const int tid = threadIdx.x;
    __shared__ __align__(16) uint4 W2l4[1024];
    __shared__ float vl[BB * 128];
    __shared__ float El2[EMB];

    if (tid < EMB) El2[tid] = E[n*EMB + tid];
    {
        const uint4* src = (const uint4*)(W2 + (size_t)n * 8192);
        #pragma unroll
        for (int r = 0; r < 4; ++r) W2l4[tid + r*256] = src[tid + r*256];
    }
    for (int idx = tid; idx < BB*128; idx += 256) {
        int b_ = idx >> 7, ki = idx & 127;
        vl[idx] = (ki < 64) ? sxin[((size_t)b_*NN + n)*DIN + ki]
                            : yin[((size_t)b_*NN + n)*DIN + (ki - 64)];
    }
    __syncthreads();

    const int b_ = tid >> 5, op = (tid & 31) * 2;
    const unsigned* W2u = (const unsigned*)W2l4;
    float a0 = 0.f, a1 = 0.f;
    #pragma unroll 4
    for (int ki = 0; ki < 128; ++ki) {
        float vv = vl[b_*128 + ki];
        unsigned w2 = W2u[ki*32 + (op >> 1)];
        float f0 = __uint_as_float(w2 << 16);
        float f1 = __uint_as_float(w2 & 0xffff0000u);
        a0 += vv * f0;
        a1 += vv * f1;
    }
    float b0 = 0.f, b1 = 0.f;
    #pragma unroll
    for (int d = 0; d < EMB; ++d) {
        float e = El2[d];
        b0 += e * bp[d*DOUT + op];
        b1 += e * bp[d*DOUT + op + 1];
    }
    *(float2*)&out[((size_t)b_*NN + n)*DOUT + op] = make_float2(a0 + b0, a1 + b1);
}

// ---------------- fallback output path (small ws): recompute W per node-chunk ----------------
#define NSTRIDE 516
__global__ __launch_bounds__(256) void k_out_fb(const float* __restrict__ E,
                                                const float* __restrict__ wp,
                                                const float* __restrict__ bp,
                                                const float* __restrict__ sxin,
                                                const float* __restrict__ yin,
                                                float* __restrict__ out) {
    const int n0 = blockIdx.x * 4;
    const int tid = threadIdx.x;
    __shared__ __align__(16) float wpch[16 * 8 * 64];
    __shared__ __align__(16) float Wl[4 * NSTRIDE];
    __shared__ float vch[32 * 8];
    __shared__ float El[4 * 16];

    if (tid < 64) El[tid] = E[n0*EMB + tid];

    const int bn = tid >> 3, og = tid & 7;
    const int b = bn >> 2, nsub = bn & 3;
    float acc[8];
    #pragma unroll
    for (int k = 0; k < 8; ++k) acc[k] = 0.0f;

    for (int ic = 0; ic < 16; ++ic) {
        __syncthreads();
        for (int idx = tid; idx < 2048; idx += 256) {
            int d = idx >> 7, isub = (idx >> 4) & 7, o4 = idx & 15;
            int gi = ic*8 + isub;
            int k = gi >> 6, i0 = gi & 63;
            ((float4*)wpch)[idx] = ((const float4*)wp)[((d*2 + k)*64 + i0)*16 + o4];
        }
        {
            int vbn = tid >> 3, visub = tid & 7;
            int vb = vbn >> 2, vns = vbn & 3;
            int nidx = (vb*NN + (n0 + vns))*DIN;
            float val;
            if (ic < 8) val = sxin[nidx + ic*8 + visub];
            else        val = yin[nidx + (ic - 8)*8 + visub];
            vch[vbn*8 + visub] = val;
        }
        __syncthreads();
        for (int e = tid; e < 512; e += 256) {
            int ns = e >> 7, isub = (e >> 4) & 7, o4 = e & 15;
            float4 s = make_float4(0.f, 0.f, 0.f, 0.f);
            #pragma unroll
            for (int d = 0; d < EMB; ++d) {
                float ev = El[ns*16 + d];
                const float4 w = *(const float4*)&wpch[(d*8 + isub)*64 + o4*4];
                s.x += ev*w.x; s.y += ev*w.y; s.z += ev*w.z; s.w += ev*w.w;
            }
            *(float4*)&Wl[ns*NSTRIDE + isub*64 + o4*4] = s;
        }
        __syncthreads();
        #pragma unroll
        for (int isub = 0; isub < 8; ++isub) {
            float wv = vch[bn*8 + isub];
            const float4 w0 = *(const float4*)&Wl[nsub*NSTRIDE + isub*64 + og*8];
            const float4 w1 = *(const float4*)&Wl[nsub*NSTRIDE + isub*64 + og*8 + 4];
            acc[0] += wv*w0.x; acc[1] += wv*w0.y; acc[2] += wv*w0.z; acc[3] += wv*w0.w;
            acc[4] += wv*w1.x; acc[5] += wv*w1.y; acc[6] += wv*w1.z; acc[7] += wv*w1.w;
        }
    }
    float4 bv0 = make_float4(0.f, 0.f, 0.f, 0.f);
    float4 bv1 = make_float4(0.f, 0.f, 0.f, 0.f);
    #pragma unroll
    for (int d = 0; d < EMB; ++d) {
        float ev = El[nsub*16 + d];
        const float4 p0 = *(const float4*)&bp[d*DOUT + og*8];
        const float4 p1 = *(const float4*)&bp[d*DOUT + og*8 + 4];
        bv0.x += ev*p0.x; bv0.y += ev*p0.y; bv0.z += ev*p0.z; bv0.w += ev*p0.w;
        bv1.x += ev*p1.x; bv1.y += ev*p1.y; bv1.z += ev*p1.z; bv1.w += ev*p1.w;
    }
    float* dst = out + ((size_t)b*NN + (n0 + nsub))*DOUT + og*8;
    *(float4*)dst       = make_float4(acc[0]+bv0.x, acc[1]+bv0.y, acc[2]+bv0.z, acc[3]+bv0.w);
    *(float4*)(dst + 4) = make_float4(acc[4]+bv1.x, acc[5]+bv1.y, acc[6]+bv1.z, acc[7]+bv1.w);
}

extern "C" void kernel_launch(void* const* d_in, const int* in_sizes, int n_in,
                              void* d_out, int out_size, void* d_ws, size_t ws_size,
                              hipStream_t stream) {
    (void)in_sizes; (void)n_in; (void)out_size;
    const float* x  = (const float*)d_in[0];
    const float* E  = (const float*)d_in[1];
    const float* pa = (const float*)d_in[2];
    const float* wp = (const float*)d_in[3];
    const float* bp = (const float*)d_in[4];
    float* out = (float*)d_out;

    unsigned short* ws16 = (unsigned short*)d_ws;
    unsigned short* sim_bf = ws16;                          // 1,048,576 us (2 MiB)
    unsigned short* xzT    = sim_bf + (size_t)NN*NN;        //   524,288 us (1 MiB)
    unsigned short* sxT    = xzT + (size_t)BB*DIN*NN;       //   524,288 us (1 MiB)
    float* sx = (float*)(sxT + (size_t)BB*DIN*NN);          //   524,288 f  (2 MiB)
    float* y  = sx + (size_t)BB*NN*DIN;                     //   524,288 f  (2 MiB)
    unsigned short* W2 = (unsigned short*)(y + (size_t)BB*NN*DIN);  // 8,388,608 us (16 MiB)

    const size_t base_bytes = 8ull*1024*1024;
    const size_t big_bytes  = base_bytes + (size_t)NN*2*DIN*DOUT*2ull;   // +16 MiB
    const bool use_big = (ws_size >= big_bytes);

    k_sim2<<<NN, 256, 0, stream>>>(E, sim_bf);
    k_z2<<<dim3(32, BB), 256, 0, stream>>>(pa, x, xzT);
    k_sx3<<<dim3(64, BB), 256, 0, stream>>>(pa, xzT, sx, sxT);
    k_y3<<<dim3(64, BB), 256, 0, stream>>>(sim_bf, sxT, y);
    if (use_big) {
        k_wgen<<<dim3(8, 32), 256, 0, stream>>>(E, wp, W2);
        k_out2<<<NN, 256, 0, stream>>>(E, bp, W2, sx, y, out);
    } else {
        k_out_fb<<<NN/4, 256, 0, stream>>>(E, wp, bp, sx, y, out);
    }
}

// Round 4
// 118.226 us; speedup vs baseline: 3.4598x; 1.2268x over previous
//
#include <hip/hip_runtime.h>

#define BB 8
#define NN 1024
#define DIN 64
#define DOUT 64
#define EMB 16
#define DPC 16

typedef __attribute__((ext_vector_type(8))) short bf16x8;
typedef __attribute__((ext_vector_type(4))) float f32x4;

__device__ inline unsigned short f2bf(float f) {
    unsigned u = __float_as_uint(f);
    u += 0x7fffu + ((u >> 16) & 1u);      // RNE (finite only)
    return (unsigned short)(u >> 16);
}

// =======================================================================
// k_front: heterogeneous kernel.
//   blocks [0,256)    : z3   — Z, Sub (bf16 exp matrix), xzT
//   blocks [256,512)  : wgen — W2[n][kio] bf16 = sum_d E[n,d] wp[d][kio]
//   blocks [512,1536) : sim  — sim_bf = bf16(softmax_rows(relu(E E^T)))
// =======================================================================
__global__ __launch_bounds__(256) void k_front(const float* __restrict__ E,
                                               const float* __restrict__ pa,
                                               const float* __restrict__ x,
                                               const float* __restrict__ wp,
                                               unsigned short* __restrict__ sim_bf,
                                               unsigned short* __restrict__ Sub,
                                               unsigned short* __restrict__ xzT,
                                               unsigned short* __restrict__ W2) {
    __shared__ __align__(16) char smem[36096];
    const int bid = blockIdx.x;
    const int tid = threadIdx.x;

    if (bid < 256) {
        // ---------------- z3: Z + Sub + xzT ----------------
        const int b = bid >> 5, c0 = (bid & 31) * 32;
        float* pa_l  = (float*)smem;                 // 512*16 f = 32 KB (later reused as xl)
        float* myp   = (float*)(smem + 32768);       // 32*16 f  = 2 KB
        float* zpart = (float*)(smem + 34816);       // 8*32 f   = 1 KB
        float* invZ  = (float*)(smem + 35840);       // 32 f

        if (tid < 128)
            ((float4*)myp)[tid] = *(const float4*)&pa[((size_t)b*NN + c0)*DPC + tid*4];
        __syncthreads();

        const int cs = tid & 31, jq = tid >> 5;
        float myc[DPC];
        #pragma unroll
        for (int p4 = 0; p4 < 4; ++p4) {
            float4 t = *(const float4*)&myp[cs*DPC + p4*4];
            myc[p4*4+0] = t.x; myc[p4*4+1] = t.y; myc[p4*4+2] = t.z; myc[p4*4+3] = t.w;
        }

        float part = 0.0f;
        for (int h = 0; h < 2; ++h) {
            __syncthreads();
            for (int i = tid; i < 512*DPC/4; i += 256)
                ((float4*)pa_l)[i] = ((const float4*)(pa + ((size_t)b*NN + h*512)*DPC))[i];
            __syncthreads();
            unsigned short* subrow = Sub + ((size_t)b*NN + (c0 + cs))*NN + h*512 + jq*64;
            for (int j4 = 0; j4 < 16; ++j4) {
                float e[4];
                #pragma unroll
                for (int t = 0; t < 4; ++t) {
                    int jj = jq*64 + j4*4 + t;
                    float s = 0.0f;
                    #pragma unroll
                    for (int p4 = 0; p4 < 4; ++p4) {
                        float4 q = *(const float4*)&pa_l[jj*DPC + p4*4];
                        s += fabsf(myc[p4*4+0]-q.x) + fabsf(myc[p4*4+1]-q.y)
                           + fabsf(myc[p4*4+2]-q.z) + fabsf(myc[p4*4+3]-q.w);
                    }
                    e[t] = __expf(-s);
                }
                part += e[0] + e[1] + e[2] + e[3];
                *(ushort4*)&subrow[j4*4] =
                    make_ushort4(f2bf(e[0]), f2bf(e[1]), f2bf(e[2]), f2bf(e[3]));
            }
        }
        zpart[jq*32 + cs] = part;
        __syncthreads();
        // reuse pa_l as xl[32][65]
        float* xl = pa_l;
        #pragma unroll
        for (int i = 0; i < 8; ++i) {
            int l = i*256 + tid, d = l & 63, c = l >> 6;
            xl[c*65 + d] = x[((size_t)b*NN + c0 + c)*DIN + d];
        }
        if (tid < 32) {
            float z = 0.f;
            #pragma unroll
            for (int q = 0; q < 8; ++q) z += zpart[q*32 + tid];
            invZ[tid] = 1.0f / z;
        }
        __syncthreads();
        #pragma unroll
        for (int i = 0; i < 8; ++i) {
            int l = i*256 + tid, c = l & 31, d = l >> 5;
            xzT[((size_t)b*DIN + d)*NN + c0 + c] = f2bf(xl[c*65 + d] * invZ[c]);
        }
    } else if (bid < 512) {
        // ---------------- wgen ----------------
        const int idx = bid - 256;
        const int kio0 = (idx & 7) * 1024 + tid * 4;
        const int n0 = (idx >> 3) * 32;
        float* El = (float*)smem;                    // 32*16 f
        if (tid < 128) *(float4*)&El[tid*4] = *(const float4*)&E[n0*EMB + tid*4];

        float4 wq[EMB];
        #pragma unroll
        for (int d = 0; d < EMB; ++d)
            wq[d] = *(const float4*)&wp[d*8192 + kio0];
        __syncthreads();

        for (int n = 0; n < 32; ++n) {
            float4 a = make_float4(0.f, 0.f, 0.f, 0.f);
            #pragma unroll
            for (int d = 0; d < EMB; ++d) {
                float e = El[n*EMB + d];
                a.x += e*wq[d].x; a.y += e*wq[d].y; a.z += e*wq[d].z; a.w += e*wq[d].w;
            }
            *(ushort4*)&W2[(size_t)(n0 + n)*8192 + kio0] =
                make_ushort4(f2bf(a.x), f2bf(a.y), f2bf(a.z), f2bf(a.w));
        }
    } else {
        // ---------------- sim ----------------
        const int i = bid - 512;
        const int lane = tid & 63, wave = tid >> 6;
        float* redw = (float*)smem;                  // 4 f

        float4 ei0 = *(const float4*)&E[i*EMB + 0];
        float4 ei1 = *(const float4*)&E[i*EMB + 4];
        float4 ei2 = *(const float4*)&E[i*EMB + 8];
        float4 ei3 = *(const float4*)&E[i*EMB + 12];

        float rv[4], tmax = -1e30f;
        #pragma unroll
        for (int k = 0; k < 4; ++k) {
            int j = tid + k*256;
            float4 a0 = *(const float4*)&E[j*EMB + 0];
            float4 a1 = *(const float4*)&E[j*EMB + 4];
            float4 a2 = *(const float4*)&E[j*EMB + 8];
            float4 a3 = *(const float4*)&E[j*EMB + 12];
            float s = ei0.x*a0.x + ei0.y*a0.y + ei0.z*a0.z + ei0.w*a0.w
                    + ei1.x*a1.x + ei1.y*a1.y + ei1.z*a1.z + ei1.w*a1.w
                    + ei2.x*a2.x + ei2.y*a2.y + ei2.z*a2.z + ei2.w*a2.w
                    + ei3.x*a3.x + ei3.y*a3.y + ei3.z*a3.z + ei3.w*a3.w;
            s = fmaxf(s, 0.0f);
            rv[k] = s; tmax = fmaxf(tmax, s);
        }
        #pragma unroll
        for (int off = 32; off > 0; off >>= 1) tmax = fmaxf(tmax, __shfl_xor(tmax, off));
        if (lane == 0) redw[wave] = tmax;
        __syncthreads();
        float rmax = fmaxf(fmaxf(redw[0], redw[1]), fmaxf(redw[2], redw[3]));
        __syncthreads();

        float ev[4], tsum = 0.f;
        #pragma unroll
        for (int k = 0; k < 4; ++k) { ev[k] = __expf(rv[k] - rmax); tsum += ev[k]; }
        #pragma unroll
        for (int off = 32; off > 0; off >>= 1) tsum += __shfl_xor(tsum, off);
        if (lane == 0) redw[wave] = tsum;
        __syncthreads();
        float inv = 1.0f / (redw[0] + redw[1] + redw[2] + redw[3]);
        #pragma unroll
        for (int k = 0; k < 4; ++k)
            sim_bf[(size_t)i*NN + tid + k*256] = f2bf(ev[k] * inv);
    }
}

// =======================================================================
// bf16 GEMM tile: C[16m x 64d] = A[16m x 1024k] * B^T[64d x 1024k]
// K-step 64, register prefetch, single LDS buffer. 4 waves: wave w owns
// d-cols w*16..w*16+15. Strides 72 give even bank spread for b128 ops.
// =======================================================================
#define ASTR 72
#define BSTR 72

__device__ inline void gemm_tile(const unsigned short* __restrict__ Arow,   // A[r][c] = Arow[r*NN+c]
                                 const unsigned short* __restrict__ Brow,   // B[d][c] = Brow[d*NN+c]
                                 unsigned short* A_l, unsigned short* B_l,
                                 int tid, f32x4& acc) {
    const int lane = tid & 63, wave = tid >> 6;
    const int q = lane >> 4, r = lane & 15;

    const int brow_ = tid >> 2, bch = (tid & 3) * 2;
    const int arow_ = tid >> 3, ach = tid & 7;

    uint4 pb0 = *(const uint4*)&Brow[(size_t)brow_*NN + (bch+0)*8];
    uint4 pb1 = *(const uint4*)&Brow[(size_t)brow_*NN + (bch+1)*8];
    uint4 pa0;
    if (tid < 128) pa0 = *(const uint4*)&Arow[(size_t)arow_*NN + ach*8];

    for (int kk = 0; kk < 16; ++kk) {
        __syncthreads();
        *(uint4*)&B_l[brow_*BSTR + (bch+0)*8] = pb0;
        *(uint4*)&B_l[brow_*BSTR + (bch+1)*8] = pb1;
        if (tid < 128) *(uint4*)&A_l[arow_*ASTR + ach*8] = pa0;
        __syncthreads();
        if (kk < 15) {
            int c1 = (kk + 1) * 64;
            pb0 = *(const uint4*)&Brow[(size_t)brow_*NN + c1 + (bch+0)*8];
            pb1 = *(const uint4*)&Brow[(size_t)brow_*NN + c1 + (bch+1)*8];
            if (tid < 128) pa0 = *(const uint4*)&Arow[(size_t)arow_*NN + c1 + ach*8];
        }
        bf16x8 a0 = *(const bf16x8*)&A_l[r*ASTR + q*8];
        bf16x8 b0 = *(const bf16x8*)&B_l[(wave*16 + r)*BSTR + q*8];
        acc = __builtin_amdgcn_mfma_f32_16x16x32_bf16(a0, b0, acc, 0, 0, 0);
        bf16x8 a1 = *(const bf16x8*)&A_l[r*ASTR + 32 + q*8];
        bf16x8 b1 = *(const bf16x8*)&B_l[(wave*16 + r)*BSTR + 32 + q*8];
        acc = __builtin_amdgcn_mfma_f32_16x16x32_bf16(a1, b1, acc, 0, 0, 0);
    }
}

// ---------------- k_sx4: sx = Sub(m-rows) @ xz ; emits sx fp32 + sxT bf16 ----------------
__global__ __launch_bounds__(256) void k_sx4(const unsigned short* __restrict__ Sub,
                                             const unsigned short* __restrict__ xzT,
                                             float* __restrict__ sx,
                                             unsigned short* __restrict__ sxT) {
    const int b = blockIdx.y, m0 = blockIdx.x * 16;
    const int tid = threadIdx.x, lane = tid & 63, wave = tid >> 6;
    __shared__ __align__(16) unsigned short A_l[16 * ASTR];
    __shared__ __align__(16) unsigned short B_l[64 * BSTR];

    f32x4 acc = {0.f, 0.f, 0.f, 0.f};
    gemm_tile(Sub + ((size_t)b*NN + m0)*NN, xzT + (size_t)b*DIN*NN, A_l, B_l, tid, acc);

    const int q = lane >> 4, r = lane & 15;
    const int d = wave*16 + r;
    const int mrow = m0 + q*4;
    #pragma unroll
    for (int reg = 0; reg < 4; ++reg)
        sx[((size_t)b*NN + mrow + reg)*DIN + d] = acc[reg];
    *(ushort4*)&sxT[((size_t)b*DIN + d)*NN + mrow] =
        make_ushort4(f2bf(acc[0]), f2bf(acc[1]), f2bf(acc[2]), f2bf(acc[3]));
}

// ---------------- k_y4: y = sim_bf(m-rows) @ sx (B from sxT) ----------------
__global__ __launch_bounds__(256) void k_y4(const unsigned short* __restrict__ sim_bf,
                                            const unsigned short* __restrict__ sxT,
                                            float* __restrict__ y) {
    const int b = blockIdx.y, m0 = blockIdx.x * 16;
    const int tid = threadIdx.x, lane = tid & 63, wave = tid >> 6;
    __shared__ __align__(16) unsigned short A_l[16 * ASTR];
    __shared__ __align__(16) unsigned short B_l[64 * BSTR];

    f32x4 acc = {0.f, 0.f, 0.f, 0.f};
    gemm_tile(sim_bf + (size_t)m0*NN, sxT + (size_t)b*DIN*NN, A_l, B_l, tid, acc);

    const int q = lane >> 4, r = lane & 15;
    const int d = wave*16 + r;
    const int mrow = m0 + q*4;
    #pragma unroll
    for (int reg = 0; reg < 4; ++reg)
        y[((size_t)b*NN + mrow + reg)*DIN + d] = acc[reg];
}

// ---------------- k_out2: out[b,n,o] = sum_ki v[b,n,ki] W2[n,ki,o] + E[n]@bp ----------------
__global__ __launch_bounds__(256) void k_out2(const float* __restrict__ E,
                                              const float* __restrict__ bp,
                                              const unsigned short* __restrict__ W2,
                                              const float* __restrict__ sxin,
                                              const float* __restrict__ yin,
                                              float* __restrict__ out) {
    const int n = blockIdx.x;
    const int tid = threadIdx.x;
    __shared__ __align__(16) uint4 W2l4[1024];
    __shared__ float vl[BB * 128];
    __shared__ float El2[EMB];

    if (tid < EMB) El2[tid] = E[n*EMB + tid];
    {
        const uint4* src = (const uint4*)(W2 + (size_t)n * 8192);
        #pragma unroll
        for (int r = 0; r < 4; ++r) W2l4[tid + r*256] = src[tid + r*256];
    }
    for (int idx = tid; idx < BB*128; idx += 256) {
        int b_ = idx >> 7, ki = idx & 127;
        vl[idx] = (ki < 64) ? sxin[((size_t)b_*NN + n)*DIN + ki]
                            : yin[((size_t)b_*NN + n)*DIN + (ki - 64)];
    }
    __syncthreads();

    const int b_ = tid >> 5, op = (tid & 31) * 2;
    const unsigned* W2u = (const unsigned*)W2l4;
    float a0 = 0.f, a1 = 0.f;
    #pragma unroll 4
    for (int ki = 0; ki < 128; ++ki) {
        float vv = vl[b_*128 + ki];
        unsigned w2 = W2u[ki*32 + (op >> 1)];
        a0 += vv * __uint_as_float(w2 << 16);
        a1 += vv * __uint_as_float(w2 & 0xffff0000u);
    }
    float b0 = 0.f, b1 = 0.f;
    #pragma unroll
    for (int d = 0; d < EMB; ++d) {
        float e = El2[d];
        b0 += e * bp[d*DOUT + op];
        b1 += e * bp[d*DOUT + op + 1];
    }
    *(float2*)&out[((size_t)b_*NN + n)*DOUT + op] = make_float2(a0 + b0, a1 + b1);
}

extern "C" void kernel_launch(void* const* d_in, const int* in_sizes, int n_in,
                              void* d_out, int out_size, void* d_ws, size_t ws_size,
                              hipStream_t stream) {
    (void)in_sizes; (void)n_in; (void)out_size; (void)ws_size;
    const float* x  = (const float*)d_in[0];
    const float* E  = (const float*)d_in[1];
    const float* pa = (const float*)d_in[2];
    const float* wp = (const float*)d_in[3];
    const float* bp = (const float*)d_in[4];
    float* out = (float*)d_out;

    // ws layout (40 MiB total; harness fill evidence shows ws ≈ 268 MB)
    unsigned short* ws16   = (unsigned short*)d_ws;
    unsigned short* sim_bf = ws16;                       // 1,048,576 us (2 MiB)
    unsigned short* xzT    = sim_bf + (size_t)NN*NN;     //   524,288 us (1 MiB)
    unsigned short* sxT    = xzT + (size_t)BB*DIN*NN;    //   524,288 us (1 MiB)
    unsigned short* Sub    = sxT + (size_t)BB*DIN*NN;    // 8,388,608 us (16 MiB)
    unsigned short* W2     = Sub + (size_t)BB*NN*NN;     // 8,388,608 us (16 MiB)
    float* sx = (float*)(W2 + (size_t)NN*2*DIN*DOUT);    //   524,288 f  (2 MiB)
    float* y  = sx + (size_t)BB*NN*DIN;                  //   524,288 f  (2 MiB)

    k_front<<<1536, 256, 0, stream>>>(E, pa, x, wp, sim_bf, Sub, xzT, W2);
    k_sx4<<<dim3(64, BB), 256, 0, stream>>>(Sub, xzT, sx, sxT);
    k_y4<<<dim3(64, BB), 256, 0, stream>>>(sim_bf, sxT, y);
    k_out2<<<NN, 256, 0, stream>>>(E, bp, W2, sx, y, out);
}